// Round 4
// baseline (397.177 us; speedup 1.0000x reference)
//
#include <hip/hip_runtime.h>

// Problem constants: B=8, N=32, T=64, D=128, E=4, H=32, BT=512, tokens M=16384
// Pipeline: K0 build Wcat -> K1 token GEMM (Q,K,V,hq,hk) -> K2 attention -> K3 Theta+LN
#define LDX 68    // LDS stride for transposed [d][tok]/[d][out] tiles (mult of 4, 68%32=4)
#define LDQ 132   // LDS stride for 32x128 tiles in K2
#define LDH 33
#define LDHT 36

// ---------------- K0: Wcat[448][128] = [Wq; Wk; Wv; W1q@Wq; W1k@Wk] ----------------
__global__ __launch_bounds__(256) void k0_build_wcat(
    const float* __restrict__ Wq, const float* __restrict__ Wk,
    const float* __restrict__ Wv, const float* __restrict__ W1,
    float* __restrict__ Wcat)
{
    __shared__ __align__(16) float Ws[128 * 132];
    const int tid = threadIdx.x;
    const int blk = blockIdx.x;
    if (blk < 12) {
        // copy rows [blk*32, blk*32+32) of [Wq;Wk;Wv]
#pragma unroll
        for (int q = 0; q < 4; ++q) {
            int f  = tid + 256 * q;        // 0..1023
            int rl = f >> 5;
            int c4 = (f & 31) * 4;
            int g  = blk * 32 + rl;        // 0..383
            const float* src = (g < 128) ? (Wq + g * 128)
                             : (g < 256) ? (Wk + (g - 128) * 128)
                                         : (Wv + (g - 256) * 128);
            *(float4*)(Wcat + (size_t)g * 128 + c4) = *(const float4*)(src + c4);
        }
    } else {
        // C[h][j] = sum_i W1part[h][i] * Wsel[i][j]   (16 rows per block)
        const int mat  = (blk - 12) >> 1;   // 0=q, 1=k
        const int half = (blk - 12) & 1;
        const float* Wsel = mat ? Wk : Wq;
#pragma unroll
        for (int q = 0; q < 16; ++q) {
            int f = tid + 256 * q;          // 0..4095
            int i = f >> 5;
            int c4 = (f & 31) * 4;
            *(float4*)(Ws + i * 132 + c4) = *(const float4*)(Wsel + i * 128 + c4);
        }
        __syncthreads();
        const int j0 = (tid & 31) * 4;
        const int h  = half * 16 + (tid >> 5) * 2;
        const float* w1a = W1 + (size_t)h * 260 + mat * 128;
        const float* w1b = W1 + (size_t)(h + 1) * 260 + mat * 128;
        float4 a0 = {0,0,0,0}, a1 = {0,0,0,0};
        for (int i = 0; i < 128; ++i) {
            float4 wv = *(const float4*)(Ws + i * 132 + j0);
            float c0 = w1a[i], c1 = w1b[i];
            a0.x = fmaf(c0, wv.x, a0.x); a0.y = fmaf(c0, wv.y, a0.y);
            a0.z = fmaf(c0, wv.z, a0.z); a0.w = fmaf(c0, wv.w, a0.w);
            a1.x = fmaf(c1, wv.x, a1.x); a1.y = fmaf(c1, wv.y, a1.y);
            a1.z = fmaf(c1, wv.z, a1.z); a1.w = fmaf(c1, wv.w, a1.w);
        }
        int g = 384 + mat * 32 + h;
        *(float4*)(Wcat + (size_t)g * 128 + j0)       = a0;
        *(float4*)(Wcat + (size_t)(g + 1) * 128 + j0) = a1;
    }
}

// ---------------- K1: Y[16384][448] = X @ Wcat^T ----------------
// grid (7, 256): x = out-tile (64), y = token-tile (64). Thread: 4 tok x 4 out.
__global__ __launch_bounds__(256, 2) void k1_token_gemm(
    const float* __restrict__ x, const float* __restrict__ Wcat,
    float* __restrict__ Y)
{
    __shared__ __align__(16) float XT[128 * LDX];   // [d][tok]
    __shared__ __align__(16) float WT[128 * LDX];   // [d][out]
    const int tid = threadIdx.x;
    const int ob  = blockIdx.x * 64;
    const int rb  = blockIdx.y * 64;
    {
        const int tk = tid >> 2, qd = tid & 3;
        const int r  = rb + tk;
        const int bt = r >> 5, n = r & 31, b = bt >> 6, t = bt & 63;
        const float* xrow = x + ((size_t)((b * 32 + n) * 64 + t)) * 128 + qd * 32;
        const float* wrow = Wcat + (size_t)(ob + tk) * 128 + qd * 32;
#pragma unroll
        for (int c = 0; c < 8; ++c) {
            int cc = (c + qd) & 7;                 // stagger: 2-way max bank conflict
            float4 vx = *(const float4*)(xrow + cc * 4);
            float4 vw = *(const float4*)(wrow + cc * 4);
            int d = qd * 32 + cc * 4;
            XT[(d + 0) * LDX + tk] = vx.x; XT[(d + 1) * LDX + tk] = vx.y;
            XT[(d + 2) * LDX + tk] = vx.z; XT[(d + 3) * LDX + tk] = vx.w;
            WT[(d + 0) * LDX + tk] = vw.x; WT[(d + 1) * LDX + tk] = vw.y;
            WT[(d + 2) * LDX + tk] = vw.z; WT[(d + 3) * LDX + tk] = vw.w;
        }
    }
    __syncthreads();
    const int o0 = (tid & 15) * 4;
    const int t0 = (tid >> 4) * 4;
    float acc[4][4];
#pragma unroll
    for (int i = 0; i < 4; ++i)
#pragma unroll
        for (int j = 0; j < 4; ++j) acc[i][j] = 0.f;
#pragma unroll 8
    for (int d = 0; d < 128; ++d) {
        float4 xa = *(const float4*)(XT + d * LDX + t0);   // broadcast across lanes
        float4 wb = *(const float4*)(WT + d * LDX + o0);   // 2-way max
        acc[0][0] = fmaf(xa.x, wb.x, acc[0][0]); acc[0][1] = fmaf(xa.x, wb.y, acc[0][1]);
        acc[0][2] = fmaf(xa.x, wb.z, acc[0][2]); acc[0][3] = fmaf(xa.x, wb.w, acc[0][3]);
        acc[1][0] = fmaf(xa.y, wb.x, acc[1][0]); acc[1][1] = fmaf(xa.y, wb.y, acc[1][1]);
        acc[1][2] = fmaf(xa.y, wb.z, acc[1][2]); acc[1][3] = fmaf(xa.y, wb.w, acc[1][3]);
        acc[2][0] = fmaf(xa.z, wb.x, acc[2][0]); acc[2][1] = fmaf(xa.z, wb.y, acc[2][1]);
        acc[2][2] = fmaf(xa.z, wb.z, acc[2][2]); acc[2][3] = fmaf(xa.z, wb.w, acc[2][3]);
        acc[3][0] = fmaf(xa.w, wb.x, acc[3][0]); acc[3][1] = fmaf(xa.w, wb.y, acc[3][1]);
        acc[3][2] = fmaf(xa.w, wb.z, acc[3][2]); acc[3][3] = fmaf(xa.w, wb.w, acc[3][3]);
    }
#pragma unroll
    for (int i = 0; i < 4; ++i) {
        int r = rb + t0 + i;
        *(float4*)(Y + (size_t)r * 448 + ob + o0) =
            make_float4(acc[i][0], acc[i][1], acc[i][2], acc[i][3]);
    }
}

// ---------------- K2: attention per bt ----------------
__global__ __launch_bounds__(256, 2) void k2_attention(
    const float* __restrict__ Y, const float* __restrict__ edge,
    const float* __restrict__ A_prior, const unsigned char* __restrict__ pad_mask,
    const float* __restrict__ Wfuse, const float* __restrict__ b1,
    const float* __restrict__ W2, const float* __restrict__ b2,
    const float* __restrict__ physw, const float* __restrict__ priorw,
    const float* __restrict__ W1,
    float* __restrict__ spat)
{
    __shared__ __align__(16) float Qs[32 * LDQ];
    __shared__ __align__(16) float Ks[32 * LDQ];
    __shared__ __align__(16) float Vs[32 * LDQ];
    __shared__ __align__(16) float hqT[32 * LDHT];   // [h][n]
    __shared__ __align__(16) float hks[32 * LDH];    // [m][h]
    __shared__ __align__(16) float Lg[32 * LDH];
    __shared__ __align__(16) float4 W1e_s[32];
    __shared__ float W2_s[32], b1s[32], maskrow[32], Wf_s[5];

    const int tid = threadIdx.x;
    const int bt  = blockIdx.x;
    const int b_  = bt >> 6;
    const float pw  = physw[0];
    const float rw_ = priorw[0];
    const float b2v = b2[0];

    // stage Y[bt] rows (32 x 448) into Q/K/V/hqT/hk
    const float* Yb = Y + (size_t)bt * 32 * 448;
#pragma unroll
    for (int q = 0; q < 14; ++q) {
        int f = tid + 256 * q;            // 0..3583
        int n = f / 112;
        int c4 = f - n * 112;
        int col = c4 * 4;
        float4 v = *(const float4*)(Yb + (size_t)n * 448 + col);
        if (col < 128)      *(float4*)(Qs + n * LDQ + col)        = v;
        else if (col < 256) *(float4*)(Ks + n * LDQ + (col-128))  = v;
        else if (col < 384) *(float4*)(Vs + n * LDQ + (col-256))  = v;
        else if (col < 416) {
            int h = col - 384;
            hqT[(h+0)*LDHT + n] = v.x; hqT[(h+1)*LDHT + n] = v.y;
            hqT[(h+2)*LDHT + n] = v.z; hqT[(h+3)*LDHT + n] = v.w;
        } else {
            int h = col - 416;
            hks[n*LDH + h+0] = v.x; hks[n*LDH + h+1] = v.y;
            hks[n*LDH + h+2] = v.z; hks[n*LDH + h+3] = v.w;
        }
    }
    if (tid < 32) {
        int h = tid;
        W1e_s[h] = *(const float4*)(W1 + (size_t)h * 260 + 256);
        W2_s[h]  = W2[h];
        b1s[h]   = b1[h];
        maskrow[h] = pad_mask[b_ * 32 + h] ? 1.f : 0.f;
        if (h < 5) Wf_s[h] = Wfuse[h];
    }
    __syncthreads();

    // logits
    {
        const int m = tid & 31, n4 = tid >> 5;
        float4 e4[4];
        float pr5[4][5];
#pragma unroll
        for (int r = 0; r < 4; ++r)
            e4[r] = *(const float4*)(edge + (((size_t)bt * 32 + (4*n4+r)) * 32 + m) * 4);
#pragma unroll
        for (int r = 0; r < 4; ++r) {
            size_t pb = (((size_t)bt * 32 + (4*n4+r)) * 32 + m) * 5;
#pragma unroll
            for (int j5 = 0; j5 < 5; ++j5) pr5[r][j5] = A_prior[pb + j5];
        }
        float accc[4] = {0,0,0,0};
        for (int j = 0; j < 128; j += 4) {
            float4 k4 = *(const float4*)(Ks + m * LDQ + j);
#pragma unroll
            for (int r = 0; r < 4; ++r) {
                float4 q4 = *(const float4*)(Qs + (4*n4+r) * LDQ + j);
                accc[r] = fmaf(q4.x, k4.x, fmaf(q4.y, k4.y, fmaf(q4.z, k4.z, fmaf(q4.w, k4.w, accc[r]))));
            }
        }
        float pacc[4] = {0,0,0,0};
        for (int h = 0; h < 32; ++h) {
            float4 we  = W1e_s[h];
            float w2v  = W2_s[h];
            float b1v  = b1s[h];
            float hkv  = hks[m * LDH + h] + b1v;
            float4 hq4 = *(const float4*)(hqT + h * LDHT + 4 * n4);
            float hqv[4] = {hq4.x, hq4.y, hq4.z, hq4.w};
#pragma unroll
            for (int r = 0; r < 4; ++r) {
                float he = fmaf(e4[r].x, we.x, fmaf(e4[r].y, we.y, fmaf(e4[r].z, we.z, e4[r].w * we.w)));
                float v  = hqv[r] + hkv + he;
                pacc[r]  = fmaf(fmaxf(v, 0.f), w2v, pacc[r]);
            }
        }
#pragma unroll
        for (int r = 0; r < 4; ++r) {
            int n = 4*n4 + r;
            float pr = pr5[r][0]*Wf_s[0] + pr5[r][1]*Wf_s[1] + pr5[r][2]*Wf_s[2]
                     + pr5[r][3]*Wf_s[3] + pr5[r][4]*Wf_s[4];
            if (!(fabsf(pr) < 1e30f)) pr = 0.f;
            pr = fmaxf(pr, 0.f);
            float lg = accc[r] * 0.08838834764831845f
                     + pw * (pacc[r] + b2v)
                     + rw_ * __logf(pr + 1e-6f);
            if (maskrow[n] != 0.f || maskrow[m] != 0.f) lg = -1e9f;
            Lg[n * LDH + m] = lg;
        }
    }
    __syncthreads();

    // softmax
    if (tid < 32) {
        const int n = tid;
        float mx = -3.4e38f;
        for (int m2 = 0; m2 < 32; ++m2) mx = fmaxf(mx, Lg[n*LDH + m2]);
        float s = 0.f;
        for (int m2 = 0; m2 < 32; ++m2) {
            float e = __expf(Lg[n*LDH + m2] - mx);
            Lg[n*LDH + m2] = e; s += e;
        }
        float inv = 1.f / s;
        for (int m2 = 0; m2 < 32; ++m2) Lg[n*LDH + m2] *= inv;
    }
    __syncthreads();

    // spatial = alpha @ V  -> global ws
    {
        const int d0 = (tid & 31) * 4;
        const int n0 = (tid >> 5) * 4;
        float sa[4][4];
#pragma unroll
        for (int r = 0; r < 4; ++r)
#pragma unroll
            for (int c = 0; c < 4; ++c) sa[r][c] = 0.f;
        for (int m = 0; m < 32; ++m) {
            float4 v4 = *(const float4*)(Vs + m * LDQ + d0);
            float a0 = Lg[(n0+0)*LDH + m], a1 = Lg[(n0+1)*LDH + m];
            float a2 = Lg[(n0+2)*LDH + m], a3 = Lg[(n0+3)*LDH + m];
            sa[0][0]=fmaf(a0,v4.x,sa[0][0]); sa[0][1]=fmaf(a0,v4.y,sa[0][1]);
            sa[0][2]=fmaf(a0,v4.z,sa[0][2]); sa[0][3]=fmaf(a0,v4.w,sa[0][3]);
            sa[1][0]=fmaf(a1,v4.x,sa[1][0]); sa[1][1]=fmaf(a1,v4.y,sa[1][1]);
            sa[1][2]=fmaf(a1,v4.z,sa[1][2]); sa[1][3]=fmaf(a1,v4.w,sa[1][3]);
            sa[2][0]=fmaf(a2,v4.x,sa[2][0]); sa[2][1]=fmaf(a2,v4.y,sa[2][1]);
            sa[2][2]=fmaf(a2,v4.z,sa[2][2]); sa[2][3]=fmaf(a2,v4.w,sa[2][3]);
            sa[3][0]=fmaf(a3,v4.x,sa[3][0]); sa[3][1]=fmaf(a3,v4.y,sa[3][1]);
            sa[3][2]=fmaf(a3,v4.z,sa[3][2]); sa[3][3]=fmaf(a3,v4.w,sa[3][3]);
        }
#pragma unroll
        for (int r = 0; r < 4; ++r)
            *(float4*)(spat + (size_t)bt * 4096 + (n0 + r) * 128 + d0) =
                make_float4(sa[r][0], sa[r][1], sa[r][2], sa[r][3]);
    }
}

// ---------------- K3: out = LN(Z + spatial @ Theta^T), masked, transposed store ----------------
__global__ __launch_bounds__(256, 2) void k3_theta_ln(
    const float* __restrict__ spat, const float* __restrict__ x,
    const float* __restrict__ Theta, const float* __restrict__ gma,
    const float* __restrict__ bta, const unsigned char* __restrict__ pad_mask,
    float* __restrict__ out)
{
    __shared__ __align__(16) float ST[128 * LDX];   // [d][tok]
    __shared__ __align__(16) float TT[128 * LDX];   // [d][o_local]
    const int tid = threadIdx.x;
    const int rb  = blockIdx.x * 64;
    {
        const int tk = tid >> 2, qd = tid & 3;
        const float* srow = spat + (size_t)(rb + tk) * 128 + qd * 32;
#pragma unroll
        for (int c = 0; c < 8; ++c) {
            int cc = (c + qd) & 7;
            float4 v = *(const float4*)(srow + cc * 4);
            int d = qd * 32 + cc * 4;
            ST[(d+0)*LDX + tk] = v.x; ST[(d+1)*LDX + tk] = v.y;
            ST[(d+2)*LDX + tk] = v.z; ST[(d+3)*LDX + tk] = v.w;
        }
    }
    const int o0 = (tid & 15) * 4;
    const int t0 = (tid >> 4) * 4;
    float yv[4][8];
#pragma unroll 1
    for (int half = 0; half < 2; ++half) {
        __syncthreads();   // covers ST staging (half0) / prior compute (half1)
        {
            const int wo = tid >> 2, qd = tid & 3;
            const float* trow = Theta + (size_t)(half * 64 + wo) * 128 + qd * 32;
#pragma unroll
            for (int c = 0; c < 8; ++c) {
                int cc = (c + qd) & 7;
                float4 v = *(const float4*)(trow + cc * 4);
                int d = qd * 32 + cc * 4;
                TT[(d+0)*LDX + wo] = v.x; TT[(d+1)*LDX + wo] = v.y;
                TT[(d+2)*LDX + wo] = v.z; TT[(d+3)*LDX + wo] = v.w;
            }
        }
        __syncthreads();
        float acc[4][4];
#pragma unroll
        for (int i = 0; i < 4; ++i)
#pragma unroll
            for (int j = 0; j < 4; ++j) acc[i][j] = 0.f;
#pragma unroll 8
        for (int d = 0; d < 128; ++d) {
            float4 xa = *(const float4*)(ST + d * LDX + t0);
            float4 wb = *(const float4*)(TT + d * LDX + o0);
            acc[0][0]=fmaf(xa.x,wb.x,acc[0][0]); acc[0][1]=fmaf(xa.x,wb.y,acc[0][1]);
            acc[0][2]=fmaf(xa.x,wb.z,acc[0][2]); acc[0][3]=fmaf(xa.x,wb.w,acc[0][3]);
            acc[1][0]=fmaf(xa.y,wb.x,acc[1][0]); acc[1][1]=fmaf(xa.y,wb.y,acc[1][1]);
            acc[1][2]=fmaf(xa.y,wb.z,acc[1][2]); acc[1][3]=fmaf(xa.y,wb.w,acc[1][3]);
            acc[2][0]=fmaf(xa.z,wb.x,acc[2][0]); acc[2][1]=fmaf(xa.z,wb.y,acc[2][1]);
            acc[2][2]=fmaf(xa.z,wb.z,acc[2][2]); acc[2][3]=fmaf(xa.z,wb.w,acc[2][3]);
            acc[3][0]=fmaf(xa.w,wb.x,acc[3][0]); acc[3][1]=fmaf(xa.w,wb.y,acc[3][1]);
            acc[3][2]=fmaf(xa.w,wb.z,acc[3][2]); acc[3][3]=fmaf(xa.w,wb.w,acc[3][3]);
        }
#pragma unroll
        for (int i = 0; i < 4; ++i)
#pragma unroll
            for (int j = 0; j < 4; ++j) yv[i][half * 4 + j] = acc[i][j];
    }
    // epilogue: residual + LayerNorm + mask + store
    float4 gA = *(const float4*)(gma + o0);
    float4 gB = *(const float4*)(gma + 64 + o0);
    float4 bA = *(const float4*)(bta + o0);
    float4 bB = *(const float4*)(bta + 64 + o0);
#pragma unroll
    for (int i = 0; i < 4; ++i) {
        int r  = rb + t0 + i;
        int bt = r >> 5, n = r & 31, b = bt >> 6, t = bt & 63;
        const float* xr = x + ((size_t)((b * 32 + n) * 64 + t)) * 128;
        float4 xA = *(const float4*)(xr + o0);
        float4 xB = *(const float4*)(xr + 64 + o0);
        float y0 = yv[i][0] + xA.x, y1 = yv[i][1] + xA.y;
        float y2 = yv[i][2] + xA.z, y3 = yv[i][3] + xA.w;
        float y4 = yv[i][4] + xB.x, y5 = yv[i][5] + xB.y;
        float y6 = yv[i][6] + xB.z, y7 = yv[i][7] + xB.w;
        float s  = ((y0+y1)+(y2+y3)) + ((y4+y5)+(y6+y7));
        float s2 = ((y0*y0+y1*y1)+(y2*y2+y3*y3)) + ((y4*y4+y5*y5)+(y6*y6+y7*y7));
#pragma unroll
        for (int off = 1; off < 16; off <<= 1) {
            s  += __shfl_xor(s,  off, 64);
            s2 += __shfl_xor(s2, off, 64);
        }
        float mu   = s * 0.0078125f;
        float var  = s2 * 0.0078125f - mu * mu;
        float rstd = rsqrtf(var + 1e-5f);
        float msk  = pad_mask[b * 32 + n] ? 0.f : 1.f;
        float4 oA, oB;
        oA.x = ((y0-mu)*rstd*gA.x + bA.x)*msk; oA.y = ((y1-mu)*rstd*gA.y + bA.y)*msk;
        oA.z = ((y2-mu)*rstd*gA.z + bA.z)*msk; oA.w = ((y3-mu)*rstd*gA.w + bA.w)*msk;
        oB.x = ((y4-mu)*rstd*gB.x + bB.x)*msk; oB.y = ((y5-mu)*rstd*gB.y + bB.y)*msk;
        oB.z = ((y6-mu)*rstd*gB.z + bB.z)*msk; oB.w = ((y7-mu)*rstd*gB.w + bB.w)*msk;
        float* op = out + ((size_t)((b * 32 + n) * 64 + t)) * 128;
        *(float4*)(op + o0)      = oA;
        *(float4*)(op + 64 + o0) = oB;
    }
}

extern "C" void kernel_launch(void* const* d_in, const int* in_sizes, int n_in,
                              void* d_out, int out_size, void* d_ws, size_t ws_size,
                              hipStream_t stream) {
    const float* x        = (const float*)d_in[0];
    const float* edge     = (const float*)d_in[1];
    const float* A_prior  = (const float*)d_in[2];
    const unsigned char* pad_mask = (const unsigned char*)d_in[3];
    const float* Wq       = (const float*)d_in[4];
    const float* Wk       = (const float*)d_in[5];
    const float* Wv       = (const float*)d_in[6];
    const float* Theta    = (const float*)d_in[7];
    const float* Wfuse    = (const float*)d_in[8];
    const float* W1       = (const float*)d_in[9];
    const float* b1       = (const float*)d_in[10];
    const float* W2       = (const float*)d_in[11];
    const float* b2       = (const float*)d_in[12];
    const float* gma      = (const float*)d_in[13];
    const float* bta      = (const float*)d_in[14];
    const float* physw    = (const float*)d_in[15];
    const float* priorw   = (const float*)d_in[16];
    float* out = (float*)d_out;

    // workspace layout (floats): Wcat[448*128] | Y[16384*448] | spat[16384*128]
    float* Wcat = (float*)d_ws;
    float* Y    = Wcat + 448 * 128;
    float* spat = Y + (size_t)16384 * 448;

    k0_build_wcat<<<dim3(16), dim3(256), 0, stream>>>(Wq, Wk, Wv, W1, Wcat);
    k1_token_gemm<<<dim3(7, 256), dim3(256), 0, stream>>>(x, Wcat, Y);
    k2_attention<<<dim3(512), dim3(256), 0, stream>>>(Y, edge, A_prior, pad_mask,
                                                      Wfuse, b1, W2, b2, physw, priorw, W1, spat);
    k3_theta_ln<<<dim3(256), dim3(256), 0, stream>>>(spat, x, Theta, gma, bta, pad_mask, out);
}

// Round 5
// 348.165 us; speedup vs baseline: 1.1408x; 1.1408x over previous
//
#include <hip/hip_runtime.h>

// B=8, N=32, T=64, D=128, E=4, H=32, BT=512
#define LDB 132   // fp32 LDS row stride for 32x128 tiles
#define LDH 33
#define LDHT 36

typedef __bf16 bf16x8 __attribute__((ext_vector_type(8)));
typedef float  f32x4  __attribute__((ext_vector_type(4)));

static __device__ __forceinline__ unsigned short f2bf(float f) {
    unsigned u = __float_as_uint(f);
    u += 0x7fffu + ((u >> 16) & 1u);        // RNE
    return (unsigned short)(u >> 16);
}
static __device__ __forceinline__ float bf2f(unsigned short u) {
    return __uint_as_float(((unsigned)u) << 16);
}
static __device__ __forceinline__ unsigned pack2(float a, float b) {
    return (unsigned)f2bf(a) | ((unsigned)f2bf(b) << 16);
}

// ---- K0: pack Wq/Wk/Wv/Theta into bf16 B-fragment order ----
// Wfrag[g][(nt*4+ks)*64 + lane] is a 16B chunk: i = nt*16+(lane&15),
// j = ks*32+(lane>>4)*8 .. +7 ; B[k=j][n=i] = W[i][j].
__global__ __launch_bounds__(256) void k0_pack_w(
    const float* __restrict__ Wq, const float* __restrict__ Wk,
    const float* __restrict__ Wv, const float* __restrict__ Theta,
    unsigned short* __restrict__ Wfrag)
{
    int gid = blockIdx.x * 256 + threadIdx.x;      // 0..8191
    int g = gid >> 11, c = gid & 2047;
    int ntk = c >> 6, lane = c & 63;
    int i = (ntk >> 2) * 16 + (lane & 15);
    int j = (ntk & 3) * 32 + (lane >> 4) * 8;
    const float* src = (g == 0 ? Wq : g == 1 ? Wk : g == 2 ? Wv : Theta) + (size_t)i * 128 + j;
    float4 a = *(const float4*)(src);
    float4 b = *(const float4*)(src + 4);
    uint4 pk;
    pk.x = pack2(a.x, a.y); pk.y = pack2(a.z, a.w);
    pk.z = pack2(b.x, b.y); pk.w = pack2(b.z, b.w);
    *(uint4*)(Wfrag + (size_t)gid * 8) = pk;
}

// ---- fused kernel: one block per bt ----
__global__ __launch_bounds__(256, 2)
void gnn_fused(const float* __restrict__ x,          // (B,N,T,D)
               const float* __restrict__ edge,       // (BT,N,N,E)
               const float* __restrict__ A_prior,    // (BT,N,N,5)
               const unsigned char* __restrict__ pad_mask,
               const unsigned short* __restrict__ Wfrag,   // packed bf16 weights
               const float* __restrict__ Wfuse,
               const float* __restrict__ W1,         // (32,260)
               const float* __restrict__ b1,
               const float* __restrict__ W2,
               const float* __restrict__ b2,
               const float* __restrict__ gma,
               const float* __restrict__ bta,
               const float* __restrict__ physw,
               const float* __restrict__ priorw,
               float* __restrict__ out)
{
    __shared__ __align__(16) float Qs[32 * LDB];            // Q fp32
    __shared__ __align__(16) float Ks[32 * LDB];            // K fp32, later Theta-out
    __shared__ __align__(16) unsigned short Zfrag[512 * 8]; // Z bf16 A-frags; later spatial frags
    __shared__ __align__(16) unsigned short Vfrag[512 * 8]; // V bf16 A-frags
    __shared__ __align__(16) float Lg[32 * LDH];
    __shared__ __align__(16) float hqT[32 * LDHT];
    __shared__ __align__(16) float hks[32 * LDH];
    __shared__ __align__(16) float4 W1e_s[32];
    __shared__ float W2_s[32], maskrow[32], Wf_s[5];

    const int tid = threadIdx.x;
    const int bt  = blockIdx.x;
    const int b_  = bt >> 6;
    const int t_  = bt & 63;
    const float pw  = physw[0];
    const float rw_ = priorw[0];
    const float b2v = b2[0];

    // ---- P0: stage Z as bf16 A-fragments ----
#pragma unroll
    for (int it = 0; it < 2; ++it) {
        int f = tid + 256 * it;             // frag chunk 0..511
        int lane9 = f & 63, ntk = f >> 6;   // ntk = Mt*4+ks
        int m = lane9 & 15, quad = lane9 >> 4;
        int n = (ntk >> 2) * 16 + m;
        int d = (ntk & 3) * 32 + quad * 8;
        const float* xr = x + ((size_t)((b_ * 32 + n) * 64 + t_)) * 128 + d;
        float4 a = *(const float4*)(xr);
        float4 b = *(const float4*)(xr + 4);
        uint4 pk;
        pk.x = pack2(a.x, a.y); pk.y = pack2(a.z, a.w);
        pk.z = pack2(b.x, b.y); pk.w = pack2(b.z, b.w);
        *(uint4*)(Zfrag + f * 8) = pk;
    }
    if (tid < 32) {
        int h = tid;
        W1e_s[h] = *(const float4*)(W1 + (size_t)h * 260 + 256);
        W2_s[h]  = W2[h];
        maskrow[h] = pad_mask[b_ * 32 + h] ? 1.f : 0.f;
        if (h < 5) Wf_s[h] = Wfuse[h];
    }
    __syncthreads();

    const int wv   = tid >> 6;        // wave 0..3
    const int lane = tid & 63;
    const int Mt   = wv & 1;
    const int ntb  = (wv >> 1) * 4;
    const int quad = lane >> 4;
    const int col0 = lane & 15;
    const bf16x8* Wf = (const bf16x8*)Wfrag;

    // ---- P1: Q,K,V MFMA (one pass, 48 MFMA/wave) ----
    {
        f32x4 zero = {0.f, 0.f, 0.f, 0.f};
        f32x4 aQ[4] = {zero, zero, zero, zero};
        f32x4 aK[4] = {zero, zero, zero, zero};
        f32x4 aV[4] = {zero, zero, zero, zero};
#pragma unroll
        for (int ks = 0; ks < 4; ++ks) {
            bf16x8 av = *(const bf16x8*)(Zfrag + ((Mt * 4 + ks) * 64 + lane) * 8);
#pragma unroll
            for (int nt = 0; nt < 4; ++nt) {
                int bi = ((ntb + nt) * 4 + ks) * 64 + lane;
                aQ[nt] = __builtin_amdgcn_mfma_f32_16x16x32_bf16(av, Wf[bi],        aQ[nt], 0, 0, 0);
                aK[nt] = __builtin_amdgcn_mfma_f32_16x16x32_bf16(av, Wf[bi + 2048], aK[nt], 0, 0, 0);
                aV[nt] = __builtin_amdgcn_mfma_f32_16x16x32_bf16(av, Wf[bi + 4096], aV[nt], 0, 0, 0);
            }
        }
#pragma unroll
        for (int nt = 0; nt < 4; ++nt) {
            int colc = (ntb + nt) * 16 + col0;
            int vks = colc >> 5, vq = (colc >> 3) & 3, vj = colc & 7;
#pragma unroll
            for (int reg = 0; reg < 4; ++reg) {
                int row = Mt * 16 + quad * 4 + reg;      // token
                Qs[row * LDB + colc] = aQ[nt][reg];
                Ks[row * LDB + colc] = aK[nt][reg];
                int idx = (Mt * 4 + vks) * 64 + vq * 16 + (quad * 4 + reg);
                Vfrag[idx * 8 + vj] = f2bf(aV[nt][reg]);
            }
        }
    }
    __syncthreads();

    // ---- P2: hq = Q @ W1q^T + b1 ([h][n]), hk = K @ W1k^T ([n][h]) ----
    {
        const int h = tid & 31, n4 = tid >> 5;
        const float* w1row = W1 + (size_t)h * 260;
        const float b1v = b1[h];
        float accq[4] = {0,0,0,0}, acck[4] = {0,0,0,0};
        for (int j = 0; j < 128; j += 4) {
            float4 wq4 = *(const float4*)(w1row + j);
            float4 wk4 = *(const float4*)(w1row + 128 + j);
#pragma unroll
            for (int r = 0; r < 4; ++r) {
                float4 q4 = *(const float4*)(Qs + (4*n4+r)*LDB + j);
                float4 k4 = *(const float4*)(Ks + (4*n4+r)*LDB + j);
                accq[r] = fmaf(q4.x, wq4.x, fmaf(q4.y, wq4.y, fmaf(q4.z, wq4.z, fmaf(q4.w, wq4.w, accq[r]))));
                acck[r] = fmaf(k4.x, wk4.x, fmaf(k4.y, wk4.y, fmaf(k4.z, wk4.z, fmaf(k4.w, wk4.w, acck[r]))));
            }
        }
#pragma unroll
        for (int r = 0; r < 4; ++r) {
            int n = 4*n4 + r;
            hqT[h * LDHT + n] = accq[r] + b1v;
            hks[n * LDH + h]  = acck[r];
        }
    }
    __syncthreads();

    // ---- P3: logits ----
    {
        const int m = tid & 31, n4 = tid >> 5;
        float4 e4[4];
        float pr5[4][5];
#pragma unroll
        for (int r = 0; r < 4; ++r)
            e4[r] = *(const float4*)(edge + (((size_t)bt * 32 + (4*n4+r)) * 32 + m) * 4);
#pragma unroll
        for (int r = 0; r < 4; ++r) {
            size_t pb = (((size_t)bt * 32 + (4*n4+r)) * 32 + m) * 5;
#pragma unroll
            for (int j5 = 0; j5 < 5; ++j5) pr5[r][j5] = A_prior[pb + j5];
        }
        float accc[4] = {0,0,0,0};
        for (int j = 0; j < 128; j += 4) {
            float4 k4 = *(const float4*)(Ks + m * LDB + j);
#pragma unroll
            for (int r = 0; r < 4; ++r) {
                float4 q4 = *(const float4*)(Qs + (4*n4+r)*LDB + j);
                accc[r] = fmaf(q4.x, k4.x, fmaf(q4.y, k4.y, fmaf(q4.z, k4.z, fmaf(q4.w, k4.w, accc[r]))));
            }
        }
        float pacc[4] = {0,0,0,0};
        for (int h = 0; h < 32; ++h) {
            float4 we  = W1e_s[h];
            float w2v  = W2_s[h];
            float hkv  = hks[m * LDH + h];
            float4 hq4 = *(const float4*)(hqT + h * LDHT + 4*n4);
            float hqv[4] = {hq4.x, hq4.y, hq4.z, hq4.w};
#pragma unroll
            for (int r = 0; r < 4; ++r) {
                float he = fmaf(e4[r].x, we.x, fmaf(e4[r].y, we.y, fmaf(e4[r].z, we.z, e4[r].w * we.w)));
                float v  = hqv[r] + hkv + he;
                pacc[r]  = fmaf(fmaxf(v, 0.f), w2v, pacc[r]);
            }
        }
#pragma unroll
        for (int r = 0; r < 4; ++r) {
            int n = 4*n4 + r;
            float pr = pr5[r][0]*Wf_s[0] + pr5[r][1]*Wf_s[1] + pr5[r][2]*Wf_s[2]
                     + pr5[r][3]*Wf_s[3] + pr5[r][4]*Wf_s[4];
            if (!(fabsf(pr) < 1e30f)) pr = 0.f;
            pr = fmaxf(pr, 0.f);
            float lg = accc[r] * 0.08838834764831845f
                     + pw * (pacc[r] + b2v)
                     + rw_ * __logf(pr + 1e-6f);
            if (maskrow[n] != 0.f || maskrow[m] != 0.f) lg = -1e9f;
            Lg[n * LDH + m] = lg;
        }
    }
    __syncthreads();

    // ---- P4: softmax ----
    if (tid < 32) {
        const int n = tid;
        float mx = -3.4e38f;
        for (int m2 = 0; m2 < 32; ++m2) mx = fmaxf(mx, Lg[n*LDH + m2]);
        float s = 0.f;
        for (int m2 = 0; m2 < 32; ++m2) {
            float e = __expf(Lg[n*LDH + m2] - mx);
            Lg[n*LDH + m2] = e; s += e;
        }
        float inv = 1.f / s;
        for (int m2 = 0; m2 < 32; ++m2) Lg[n*LDH + m2] *= inv;
    }
    __syncthreads();

    // ---- P6: spatial = alpha @ V -> bf16 A-frags (into Zfrag) ----
    {
        const int d0 = (tid & 31) * 4;
        const int n0 = (tid >> 5) * 4;
        const int vks = d0 >> 5, vq = (d0 >> 3) & 3, vj = d0 & 7;
        float sa[4][4];
#pragma unroll
        for (int r = 0; r < 4; ++r)
#pragma unroll
            for (int c = 0; c < 4; ++c) sa[r][c] = 0.f;
        for (int m = 0; m < 32; ++m) {
            int idx = ((m >> 4) * 4 + vks) * 64 + vq * 16 + (m & 15);
            const unsigned short* vp = Vfrag + idx * 8 + vj;
            float v0 = bf2f(vp[0]), v1 = bf2f(vp[1]), v2 = bf2f(vp[2]), v3 = bf2f(vp[3]);
            float a0 = Lg[(n0+0)*LDH + m], a1 = Lg[(n0+1)*LDH + m];
            float a2 = Lg[(n0+2)*LDH + m], a3 = Lg[(n0+3)*LDH + m];
            sa[0][0]=fmaf(a0,v0,sa[0][0]); sa[0][1]=fmaf(a0,v1,sa[0][1]); sa[0][2]=fmaf(a0,v2,sa[0][2]); sa[0][3]=fmaf(a0,v3,sa[0][3]);
            sa[1][0]=fmaf(a1,v0,sa[1][0]); sa[1][1]=fmaf(a1,v1,sa[1][1]); sa[1][2]=fmaf(a1,v2,sa[1][2]); sa[1][3]=fmaf(a1,v3,sa[1][3]);
            sa[2][0]=fmaf(a2,v0,sa[2][0]); sa[2][1]=fmaf(a2,v1,sa[2][1]); sa[2][2]=fmaf(a2,v2,sa[2][2]); sa[2][3]=fmaf(a2,v3,sa[2][3]);
            sa[3][0]=fmaf(a3,v0,sa[3][0]); sa[3][1]=fmaf(a3,v1,sa[3][1]); sa[3][2]=fmaf(a3,v2,sa[3][2]); sa[3][3]=fmaf(a3,v3,sa[3][3]);
        }
#pragma unroll
        for (int r = 0; r < 4; ++r) {
            int n = n0 + r;
            int idx = ((n >> 4) * 4 + vks) * 64 + vq * 16 + (n & 15);
            unsigned short* sp = Zfrag + idx * 8 + vj;
            sp[0] = f2bf(sa[r][0]); sp[1] = f2bf(sa[r][1]);
            sp[2] = f2bf(sa[r][2]); sp[3] = f2bf(sa[r][3]);
        }
    }
    __syncthreads();

    // ---- P7: Theta MFMA (16 MFMA/wave) -> Ks (fp32) ----
    {
        f32x4 zero = {0.f, 0.f, 0.f, 0.f};
        f32x4 aT[4] = {zero, zero, zero, zero};
#pragma unroll
        for (int ks = 0; ks < 4; ++ks) {
            bf16x8 av = *(const bf16x8*)(Zfrag + ((Mt * 4 + ks) * 64 + lane) * 8);
#pragma unroll
            for (int nt = 0; nt < 4; ++nt) {
                int bi = (3 * 32 + (ntb + nt) * 4 + ks) * 64 + lane;
                aT[nt] = __builtin_amdgcn_mfma_f32_16x16x32_bf16(av, Wf[bi], aT[nt], 0, 0, 0);
            }
        }
#pragma unroll
        for (int nt = 0; nt < 4; ++nt) {
            int colc = (ntb + nt) * 16 + col0;
#pragma unroll
            for (int reg = 0; reg < 4; ++reg) {
                int row = Mt * 16 + quad * 4 + reg;
                Ks[row * LDB + colc] = aT[nt][reg];
            }
        }
    }
    __syncthreads();

    // ---- P8: y = x + Theta-out; LayerNorm; mask; store ----
    {
        const int d0 = (tid & 31) * 4;
        const int n0 = (tid >> 5) * 4;
        float4 g4  = *(const float4*)(gma + d0);
        float4 be4 = *(const float4*)(bta + d0);
#pragma unroll
        for (int r = 0; r < 4; ++r) {
            const int n = n0 + r;
            const float* xr = x + ((size_t)((b_ * 32 + n) * 64 + t_)) * 128 + d0;
            float4 z  = *(const float4*)(xr);
            float4 th = *(const float4*)(Ks + n * LDB + d0);
            float y0 = th.x + z.x, y1 = th.y + z.y, y2 = th.z + z.z, y3 = th.w + z.w;
            float s  = (y0 + y1) + (y2 + y3);
            float s2 = (y0*y0 + y1*y1) + (y2*y2 + y3*y3);
#pragma unroll
            for (int off = 1; off < 32; off <<= 1) {
                s  += __shfl_xor(s,  off, 64);
                s2 += __shfl_xor(s2, off, 64);
            }
            float mu   = s * 0.0078125f;
            float var  = s2 * 0.0078125f - mu * mu;
            float rstd = rsqrtf(var + 1e-5f);
            float msk  = (maskrow[n] != 0.f) ? 0.f : 1.f;
            float4 o;
            o.x = ((y0 - mu) * rstd * g4.x + be4.x) * msk;
            o.y = ((y1 - mu) * rstd * g4.y + be4.y) * msk;
            o.z = ((y2 - mu) * rstd * g4.z + be4.z) * msk;
            o.w = ((y3 - mu) * rstd * g4.w + be4.w) * msk;
            *(float4*)(out + ((size_t)((b_ * 32 + n) * 64 + t_)) * 128 + d0) = o;
        }
    }
}

extern "C" void kernel_launch(void* const* d_in, const int* in_sizes, int n_in,
                              void* d_out, int out_size, void* d_ws, size_t ws_size,
                              hipStream_t stream) {
    const float* x        = (const float*)d_in[0];
    const float* edge     = (const float*)d_in[1];
    const float* A_prior  = (const float*)d_in[2];
    const unsigned char* pad_mask = (const unsigned char*)d_in[3];
    const float* Wq       = (const float*)d_in[4];
    const float* Wk       = (const float*)d_in[5];
    const float* Wv       = (const float*)d_in[6];
    const float* Theta    = (const float*)d_in[7];
    const float* Wfuse    = (const float*)d_in[8];
    const float* W1       = (const float*)d_in[9];
    const float* b1       = (const float*)d_in[10];
    const float* W2       = (const float*)d_in[11];
    const float* b2       = (const float*)d_in[12];
    const float* gma      = (const float*)d_in[13];
    const float* bta      = (const float*)d_in[14];
    const float* physw    = (const float*)d_in[15];
    const float* priorw   = (const float*)d_in[16];
    float* out = (float*)d_out;

    unsigned short* Wfrag = (unsigned short*)d_ws;   // 4 x 2048 x 16B = 128 KB

    k0_pack_w<<<dim3(32), dim3(256), 0, stream>>>(Wq, Wk, Wv, Theta, Wfrag);
    gnn_fused<<<dim3(512), dim3(256), 0, stream>>>(
        x, edge, A_prior, pad_mask, Wfrag, Wfuse,
        W1, b1, W2, b2, gma, bta, physw, priorw, out);
}

// Round 6
// 347.855 us; speedup vs baseline: 1.1418x; 1.0009x over previous
//
#include <hip/hip_runtime.h>

// B=8, N=32, T=64, D=128, E=4, H=32, BT=512
#define LDB 132   // fp32 LDS row stride for 32x128 tiles
#define LDH 33
#define LDHT 36

typedef __bf16 bf16x8 __attribute__((ext_vector_type(8)));
typedef float  f32x4  __attribute__((ext_vector_type(4)));

static __device__ __forceinline__ unsigned short f2bf(float f) {
    unsigned u = __float_as_uint(f);
    u += 0x7fffu + ((u >> 16) & 1u);        // RNE
    return (unsigned short)(u >> 16);
}
static __device__ __forceinline__ float bf2f(unsigned short u) {
    return __uint_as_float(((unsigned)u) << 16);
}
static __device__ __forceinline__ unsigned pack2(float a, float b) {
    return (unsigned)f2bf(a) | ((unsigned)f2bf(b) << 16);
}

// Wfrag layout (shorts): [g=0..3: Wq,Wk,Wv,Theta][2048 chunks][8]
// then composite: base 65536 + mat*4096: [mat=0: Cq=W1q@Wq, mat=1: Ck=W1k@Wk]
// B-frag chunk (nt*4+ks)*64+lane holds B[k=j][n]: n = nt*16+(lane&15),
// j = ks*32+(lane>>4)*8+vj.

// ---- K0a: pack Wq/Wk/Wv/Theta into bf16 B-frag order ----
__global__ __launch_bounds__(256) void k0a_pack_w(
    const float* __restrict__ Wq, const float* __restrict__ Wk,
    const float* __restrict__ Wv, const float* __restrict__ Theta,
    unsigned short* __restrict__ Wfrag)
{
    int gid = blockIdx.x * 256 + threadIdx.x;      // 0..8191
    int g = gid >> 11, c = gid & 2047;
    int ntk = c >> 6, lane = c & 63;
    int i = (ntk >> 2) * 16 + (lane & 15);
    int j = (ntk & 3) * 32 + (lane >> 4) * 8;
    const float* src = (g == 0 ? Wq : g == 1 ? Wk : g == 2 ? Wv : Theta) + (size_t)i * 128 + j;
    float4 a = *(const float4*)(src);
    float4 b = *(const float4*)(src + 4);
    uint4 pk;
    pk.x = pack2(a.x, a.y); pk.y = pack2(a.z, a.w);
    pk.z = pack2(b.x, b.y); pk.w = pack2(b.z, b.w);
    *(uint4*)(Wfrag + (size_t)gid * 8) = pk;
}

// ---- K0b: Cq = W1q@Wq, Ck = W1k@Wk (32x128 fp32) -> bf16 B-frags ----
// grid 8: mat = blk&1, hbase = (blk>>1)*8. Each block: stage Wsel + W1 rows in LDS.
__global__ __launch_bounds__(256, 1) void k0b_compose(
    const float* __restrict__ Wq, const float* __restrict__ Wk,
    const float* __restrict__ W1, unsigned short* __restrict__ Wfrag)
{
    __shared__ __align__(16) float Ws[128 * 132];
    __shared__ __align__(16) float W1s[8 * 128];
    const int tid = threadIdx.x;
    const int mat   = blockIdx.x & 1;
    const int hbase = (blockIdx.x >> 1) * 8;
    const float* Wsel = mat ? Wk : Wq;
#pragma unroll
    for (int q = 0; q < 16; ++q) {
        int f = tid + 256 * q;              // 0..4095
        int i = f >> 5, c4 = (f & 31) * 4;
        *(float4*)(Ws + i * 132 + c4) = *(const float4*)(Wsel + (size_t)i * 128 + c4);
    }
#pragma unroll
    for (int q = 0; q < 4; ++q) {
        int f = tid + 256 * q;              // 0..1023
        int hl = f >> 7, i = f & 127;
        W1s[hl * 128 + i] = W1[(size_t)(hbase + hl) * 260 + mat * 128 + i];
    }
    __syncthreads();
    const int hl = tid >> 5;                // 0..7
    const int h  = hbase + hl;
    const int j0 = (tid & 31) * 4;
    float4 acc = {0.f, 0.f, 0.f, 0.f};
    for (int i = 0; i < 128; ++i) {
        float c = W1s[hl * 128 + i];
        float4 w = *(const float4*)(Ws + i * 132 + j0);
        acc.x = fmaf(c, w.x, acc.x); acc.y = fmaf(c, w.y, acc.y);
        acc.z = fmaf(c, w.z, acc.z); acc.w = fmaf(c, w.w, acc.w);
    }
    const int nt = h >> 4;
    const unsigned base = 65536u + (unsigned)mat * 4096u;
    float av[4] = {acc.x, acc.y, acc.z, acc.w};
#pragma unroll
    for (int jj = 0; jj < 4; ++jj) {
        int j = j0 + jj;
        int lane = (h & 15) | (((j >> 3) & 3) << 4);
        int ks = j >> 5, vj = j & 7;
        Wfrag[base + (unsigned)((nt * 4 + ks) * 64 + lane) * 8 + vj] = f2bf(av[jj]);
    }
}

// ---- fused kernel: one block per bt ----
__global__ __launch_bounds__(256, 2)
void gnn_fused(const float* __restrict__ x,          // (B,N,T,D)
               const float* __restrict__ edge,       // (BT,N,N,E)
               const float* __restrict__ A_prior,    // (BT,N,N,5)
               const unsigned char* __restrict__ pad_mask,
               const unsigned short* __restrict__ Wfrag,
               const float* __restrict__ Wfuse,
               const float* __restrict__ W1,         // (32,260)
               const float* __restrict__ b1,
               const float* __restrict__ W2,
               const float* __restrict__ b2,
               const float* __restrict__ gma,
               const float* __restrict__ bta,
               const float* __restrict__ physw,
               const float* __restrict__ priorw,
               float* __restrict__ out)
{
    __shared__ __align__(16) float Qs[32 * LDB];            // Q fp32
    __shared__ __align__(16) float Ks[32 * LDB];            // K fp32, later Theta-out
    __shared__ __align__(16) unsigned short Zfrag[512 * 8]; // Z bf16 A-frags; later spatial
    __shared__ __align__(16) unsigned short Vfrag[512 * 8]; // V bf16 A-frags
    __shared__ __align__(16) float Lg[32 * LDH];
    __shared__ __align__(16) float hqT[32 * LDHT];          // [h][n], b1 folded
    __shared__ __align__(16) float hks[32 * LDH];           // [n][h]
    __shared__ __align__(16) float4 W1e_s[32];
    __shared__ float W2_s[32], b1s[32], maskrow[32], Wf_s[5];

    const int tid = threadIdx.x;
    const int bt  = blockIdx.x;
    const int b_  = bt >> 6;
    const int t_  = bt & 63;
    const float pw  = physw[0];
    const float rw_ = priorw[0];
    const float b2v = b2[0];

    // ---- P0: prefetch edge/prior into regs; stage Z as bf16 A-frags ----
    const int m3 = tid & 31, n43 = tid >> 5;   // P3 mapping, used for prefetch
    float4 e4[4];
    float pr5[4][5];
#pragma unroll
    for (int r = 0; r < 4; ++r)
        e4[r] = *(const float4*)(edge + (((size_t)bt * 32 + (4*n43+r)) * 32 + m3) * 4);
#pragma unroll
    for (int r = 0; r < 4; ++r) {
        size_t pb = (((size_t)bt * 32 + (4*n43+r)) * 32 + m3) * 5;
#pragma unroll
        for (int j5 = 0; j5 < 5; ++j5) pr5[r][j5] = A_prior[pb + j5];
    }
#pragma unroll
    for (int it = 0; it < 2; ++it) {
        int f = tid + 256 * it;             // frag chunk 0..511
        int lane9 = f & 63, ntk = f >> 6;
        int mm = lane9 & 15, qq = lane9 >> 4;
        int n = (ntk >> 2) * 16 + mm;
        int d = (ntk & 3) * 32 + qq * 8;
        const float* xr = x + ((size_t)((b_ * 32 + n) * 64 + t_)) * 128 + d;
        float4 a = *(const float4*)(xr);
        float4 b = *(const float4*)(xr + 4);
        uint4 pk;
        pk.x = pack2(a.x, a.y); pk.y = pack2(a.z, a.w);
        pk.z = pack2(b.x, b.y); pk.w = pack2(b.z, b.w);
        *(uint4*)(Zfrag + f * 8) = pk;
    }
    if (tid < 32) {
        int h = tid;
        W1e_s[h] = *(const float4*)(W1 + (size_t)h * 260 + 256);
        W2_s[h]  = W2[h];
        b1s[h]   = b1[h];
        maskrow[h] = pad_mask[b_ * 32 + h] ? 1.f : 0.f;
        if (h < 5) Wf_s[h] = Wfuse[h];
    }
    __syncthreads();

    const int wv   = tid >> 6;        // wave 0..3
    const int lane = tid & 63;
    const int Mt   = wv & 1;          // token half
    const int cgrp = wv >> 1;         // column half for Q/K/V
    const int quad = lane >> 4;
    const int col0 = lane & 15;
    const bf16x8* Wf = (const bf16x8*)Wfrag;

    // ---- P1: Q,K,V + hq,hk MFMA (56 MFMA/wave) ----
    {
        f32x4 zero = {0.f, 0.f, 0.f, 0.f};
        f32x4 aQ[4] = {zero, zero, zero, zero};
        f32x4 aK[4] = {zero, zero, zero, zero};
        f32x4 aV[4] = {zero, zero, zero, zero};
        f32x4 aE[2] = {zero, zero};
        const int emat = wv >> 1;     // 0 = hq (waves 0,1), 1 = hk (waves 2,3)
#pragma unroll
        for (int ks = 0; ks < 4; ++ks) {
            bf16x8 av = *(const bf16x8*)(Zfrag + ((Mt * 4 + ks) * 64 + lane) * 8);
#pragma unroll
            for (int nt = 0; nt < 4; ++nt) {
                int bi = ((cgrp * 4 + nt) * 4 + ks) * 64 + lane;
                aQ[nt] = __builtin_amdgcn_mfma_f32_16x16x32_bf16(av, Wf[bi],        aQ[nt], 0, 0, 0);
                aK[nt] = __builtin_amdgcn_mfma_f32_16x16x32_bf16(av, Wf[bi + 2048], aK[nt], 0, 0, 0);
                aV[nt] = __builtin_amdgcn_mfma_f32_16x16x32_bf16(av, Wf[bi + 4096], aV[nt], 0, 0, 0);
            }
#pragma unroll
            for (int nt = 0; nt < 2; ++nt) {
                int bi = 8192 + emat * 512 + (nt * 4 + ks) * 64 + lane;
                aE[nt] = __builtin_amdgcn_mfma_f32_16x16x32_bf16(av, Wf[bi], aE[nt], 0, 0, 0);
            }
        }
#pragma unroll
        for (int nt = 0; nt < 4; ++nt) {
            int colc = (cgrp * 4 + nt) * 16 + col0;
            int vks = colc >> 5, vq = (colc >> 3) & 3, vj = colc & 7;
#pragma unroll
            for (int reg = 0; reg < 4; ++reg) {
                int row = Mt * 16 + quad * 4 + reg;      // token
                Qs[row * LDB + colc] = aQ[nt][reg];
                Ks[row * LDB + colc] = aK[nt][reg];
                int idx = (Mt * 4 + vks) * 64 + vq * 16 + (quad * 4 + reg);
                Vfrag[idx * 8 + vj] = f2bf(aV[nt][reg]);
            }
        }
#pragma unroll
        for (int nt = 0; nt < 2; ++nt) {
            int h = nt * 16 + col0;
#pragma unroll
            for (int reg = 0; reg < 4; ++reg) {
                int n = Mt * 16 + quad * 4 + reg;        // token
                if (emat == 0) hqT[h * LDHT + n] = aE[nt][reg] + b1s[h];
                else           hks[n * LDH + h]  = aE[nt][reg];
            }
        }
    }
    __syncthreads();

    // ---- P3: logits = QK^T/sqrt(d) + pw*phys + rw*log(prior+1e-6), masked ----
    {
        const int m = m3, n4 = n43;
        float accc[4] = {0,0,0,0};
        for (int j = 0; j < 128; j += 4) {
            float4 k4 = *(const float4*)(Ks + m * LDB + j);
#pragma unroll
            for (int r = 0; r < 4; ++r) {
                float4 q4 = *(const float4*)(Qs + (4*n4+r)*LDB + j);
                accc[r] = fmaf(q4.x, k4.x, fmaf(q4.y, k4.y, fmaf(q4.z, k4.z, fmaf(q4.w, k4.w, accc[r]))));
            }
        }
        float pacc[4] = {0,0,0,0};
        for (int h = 0; h < 32; ++h) {
            float4 we  = W1e_s[h];
            float w2v  = W2_s[h];
            float hkv  = hks[m * LDH + h];
            float4 hq4 = *(const float4*)(hqT + h * LDHT + 4*n4);
            float hqv[4] = {hq4.x, hq4.y, hq4.z, hq4.w};
#pragma unroll
            for (int r = 0; r < 4; ++r) {
                float he = fmaf(e4[r].x, we.x, fmaf(e4[r].y, we.y, fmaf(e4[r].z, we.z, e4[r].w * we.w)));
                float v  = hqv[r] + hkv + he;
                pacc[r]  = fmaf(fmaxf(v, 0.f), w2v, pacc[r]);
            }
        }
#pragma unroll
        for (int r = 0; r < 4; ++r) {
            int n = 4*n4 + r;
            float pr = pr5[r][0]*Wf_s[0] + pr5[r][1]*Wf_s[1] + pr5[r][2]*Wf_s[2]
                     + pr5[r][3]*Wf_s[3] + pr5[r][4]*Wf_s[4];
            if (!(fabsf(pr) < 1e30f)) pr = 0.f;
            pr = fmaxf(pr, 0.f);
            float lg = accc[r] * 0.08838834764831845f
                     + pw * (pacc[r] + b2v)
                     + rw_ * __logf(pr + 1e-6f);
            if (maskrow[n] != 0.f || maskrow[m] != 0.f) lg = -1e9f;
            Lg[n * LDH + m] = lg;
        }
    }
    __syncthreads();

    // ---- P4: softmax ----
    if (tid < 32) {
        const int n = tid;
        float mx = -3.4e38f;
        for (int m2 = 0; m2 < 32; ++m2) mx = fmaxf(mx, Lg[n*LDH + m2]);
        float s = 0.f;
        for (int m2 = 0; m2 < 32; ++m2) {
            float e = __expf(Lg[n*LDH + m2] - mx);
            Lg[n*LDH + m2] = e; s += e;
        }
        float inv = 1.f / s;
        for (int m2 = 0; m2 < 32; ++m2) Lg[n*LDH + m2] *= inv;
    }
    __syncthreads();

    // ---- P6: spatial = alpha @ V -> bf16 A-frags (into Zfrag) ----
    {
        const int d0 = (tid & 31) * 4;
        const int n0 = (tid >> 5) * 4;
        const int vks = d0 >> 5, vq = (d0 >> 3) & 3, vj = d0 & 7;
        float sa[4][4];
#pragma unroll
        for (int r = 0; r < 4; ++r)
#pragma unroll
            for (int c = 0; c < 4; ++c) sa[r][c] = 0.f;
        for (int m = 0; m < 32; ++m) {
            int idx = ((m >> 4) * 4 + vks) * 64 + vq * 16 + (m & 15);
            const unsigned short* vp = Vfrag + idx * 8 + vj;
            float v0 = bf2f(vp[0]), v1 = bf2f(vp[1]), v2 = bf2f(vp[2]), v3 = bf2f(vp[3]);
            float a0 = Lg[(n0+0)*LDH + m], a1 = Lg[(n0+1)*LDH + m];
            float a2 = Lg[(n0+2)*LDH + m], a3 = Lg[(n0+3)*LDH + m];
            sa[0][0]=fmaf(a0,v0,sa[0][0]); sa[0][1]=fmaf(a0,v1,sa[0][1]); sa[0][2]=fmaf(a0,v2,sa[0][2]); sa[0][3]=fmaf(a0,v3,sa[0][3]);
            sa[1][0]=fmaf(a1,v0,sa[1][0]); sa[1][1]=fmaf(a1,v1,sa[1][1]); sa[1][2]=fmaf(a1,v2,sa[1][2]); sa[1][3]=fmaf(a1,v3,sa[1][3]);
            sa[2][0]=fmaf(a2,v0,sa[2][0]); sa[2][1]=fmaf(a2,v1,sa[2][1]); sa[2][2]=fmaf(a2,v2,sa[2][2]); sa[2][3]=fmaf(a2,v3,sa[2][3]);
            sa[3][0]=fmaf(a3,v0,sa[3][0]); sa[3][1]=fmaf(a3,v1,sa[3][1]); sa[3][2]=fmaf(a3,v2,sa[3][2]); sa[3][3]=fmaf(a3,v3,sa[3][3]);
        }
#pragma unroll
        for (int r = 0; r < 4; ++r) {
            int n = n0 + r;
            int idx = ((n >> 4) * 4 + vks) * 64 + vq * 16 + (n & 15);
            unsigned short* sp = Zfrag + idx * 8 + vj;
            sp[0] = f2bf(sa[r][0]); sp[1] = f2bf(sa[r][1]);
            sp[2] = f2bf(sa[r][2]); sp[3] = f2bf(sa[r][3]);
        }
    }
    __syncthreads();

    // ---- P7: Theta MFMA (16 MFMA/wave) -> Ks (fp32) ----
    {
        f32x4 zero = {0.f, 0.f, 0.f, 0.f};
        f32x4 aT[4] = {zero, zero, zero, zero};
#pragma unroll
        for (int ks = 0; ks < 4; ++ks) {
            bf16x8 av = *(const bf16x8*)(Zfrag + ((Mt * 4 + ks) * 64 + lane) * 8);
#pragma unroll
            for (int nt = 0; nt < 4; ++nt) {
                int bi = (3 * 32 + (cgrp * 4 + nt) * 4 + ks) * 64 + lane;
                aT[nt] = __builtin_amdgcn_mfma_f32_16x16x32_bf16(av, Wf[bi], aT[nt], 0, 0, 0);
            }
        }
#pragma unroll
        for (int nt = 0; nt < 4; ++nt) {
            int colc = (cgrp * 4 + nt) * 16 + col0;
#pragma unroll
            for (int reg = 0; reg < 4; ++reg) {
                int row = Mt * 16 + quad * 4 + reg;
                Ks[row * LDB + colc] = aT[nt][reg];
            }
        }
    }
    __syncthreads();

    // ---- P8: y = x + Theta-out; LayerNorm; mask; store ----
    {
        const int d0 = (tid & 31) * 4;
        const int n0 = (tid >> 5) * 4;
        float4 g4  = *(const float4*)(gma + d0);
        float4 be4 = *(const float4*)(bta + d0);
#pragma unroll
        for (int r = 0; r < 4; ++r) {
            const int n = n0 + r;
            const float* xr = x + ((size_t)((b_ * 32 + n) * 64 + t_)) * 128 + d0;
            float4 z  = *(const float4*)(xr);
            float4 th = *(const float4*)(Ks + n * LDB + d0);
            float y0 = th.x + z.x, y1 = th.y + z.y, y2 = th.z + z.z, y3 = th.w + z.w;
            float s  = (y0 + y1) + (y2 + y3);
            float s2 = (y0*y0 + y1*y1) + (y2*y2 + y3*y3);
#pragma unroll
            for (int off = 1; off < 32; off <<= 1) {
                s  += __shfl_xor(s,  off, 64);
                s2 += __shfl_xor(s2, off, 64);
            }
            float mu   = s * 0.0078125f;
            float var  = s2 * 0.0078125f - mu * mu;
            float rstd = rsqrtf(var + 1e-5f);
            float msk  = (maskrow[n] != 0.f) ? 0.f : 1.f;
            float4 o;
            o.x = ((y0 - mu) * rstd * g4.x + be4.x) * msk;
            o.y = ((y1 - mu) * rstd * g4.y + be4.y) * msk;
            o.z = ((y2 - mu) * rstd * g4.z + be4.z) * msk;
            o.w = ((y3 - mu) * rstd * g4.w + be4.w) * msk;
            *(float4*)(out + ((size_t)((b_ * 32 + n) * 64 + t_)) * 128 + d0) = o;
        }
    }
}

extern "C" void kernel_launch(void* const* d_in, const int* in_sizes, int n_in,
                              void* d_out, int out_size, void* d_ws, size_t ws_size,
                              hipStream_t stream) {
    const float* x        = (const float*)d_in[0];
    const float* edge     = (const float*)d_in[1];
    const float* A_prior  = (const float*)d_in[2];
    const unsigned char* pad_mask = (const unsigned char*)d_in[3];
    const float* Wq       = (const float*)d_in[4];
    const float* Wk       = (const float*)d_in[5];
    const float* Wv       = (const float*)d_in[6];
    const float* Theta    = (const float*)d_in[7];
    const float* Wfuse    = (const float*)d_in[8];
    const float* W1       = (const float*)d_in[9];
    const float* b1       = (const float*)d_in[10];
    const float* W2       = (const float*)d_in[11];
    const float* b2       = (const float*)d_in[12];
    const float* gma      = (const float*)d_in[13];
    const float* bta      = (const float*)d_in[14];
    const float* physw    = (const float*)d_in[15];
    const float* priorw   = (const float*)d_in[16];
    float* out = (float*)d_out;

    unsigned short* Wfrag = (unsigned short*)d_ws;   // 73728 shorts = 144 KB

    k0a_pack_w<<<dim3(32), dim3(256), 0, stream>>>(Wq, Wk, Wv, Theta, Wfrag);
    k0b_compose<<<dim3(8), dim3(256), 0, stream>>>(Wq, Wk, W1, Wfrag);
    gnn_fused<<<dim3(512), dim3(256), 0, stream>>>(
        x, edge, A_prior, pad_mask, Wfrag, Wfuse,
        W1, b1, W2, b2, gma, bta, physw, priorw, out);
}

// Round 9
// 285.372 us; speedup vs baseline: 1.3918x; 1.2190x over previous
//
#include <hip/hip_runtime.h>

// B=8, N=32, T=64, D=128, E=4, H=32, BT=512
// R9: half-block structure (grid 1024, 16 Q-rows/block) at 4 blocks/CU,
// with R6-validated numerics: fp32 Q/K in LDS + fp32 VALU QK^T content.
// MFMA only for Q/K/V/hq/hk projections and Theta (validated in R5/R6).

typedef __bf16 bf16x8 __attribute__((ext_vector_type(8)));
typedef float  f32x4  __attribute__((ext_vector_type(4)));

static __device__ __forceinline__ unsigned short f2bf(float f) {
    unsigned u = __float_as_uint(f);
    u += 0x7fffu + ((u >> 16) & 1u);        // RNE
    return (unsigned short)(u >> 16);
}
static __device__ __forceinline__ float bf2f(unsigned short u) {
    return __uint_as_float(((unsigned)u) << 16);
}
static __device__ __forceinline__ unsigned pack2(float a, float b) {
    return (unsigned)f2bf(a) | ((unsigned)f2bf(b) << 16);
}

// Wfrag (16B chunks): [0,2048) Wq | [2048,4096) Wk | [4096,6144) Wv |
// [6144,8192) Theta | chunk 8192+: Cq=W1q@Wq (512), chunk 8704+: Ck=W1k@Wk (512).
// B-frag chunk (nt*4+ks)*64+lane holds B[k=j][n]: n = nt*16+(lane&15),
// j = ks*32+(lane>>4)*8 + (0..7).
__global__ __launch_bounds__(256) void k0a_pack_w(
    const float* __restrict__ Wq, const float* __restrict__ Wk,
    const float* __restrict__ Wv, const float* __restrict__ Theta,
    unsigned short* __restrict__ Wfrag)
{
    int gid = blockIdx.x * 256 + threadIdx.x;      // 0..8191
    int g = gid >> 11, c = gid & 2047;
    int ntk = c >> 6, lane = c & 63;
    int i = (ntk >> 2) * 16 + (lane & 15);
    int j = (ntk & 3) * 32 + (lane >> 4) * 8;
    const float* src = (g == 0 ? Wq : g == 1 ? Wk : g == 2 ? Wv : Theta) + (size_t)i * 128 + j;
    float4 a = *(const float4*)(src);
    float4 b = *(const float4*)(src + 4);
    uint4 pk;
    pk.x = pack2(a.x, a.y); pk.y = pack2(a.z, a.w);
    pk.z = pack2(b.x, b.y); pk.w = pack2(b.z, b.w);
    *(uint4*)(Wfrag + (size_t)gid * 8) = pk;
}

__global__ __launch_bounds__(256, 1) void k0b_compose(
    const float* __restrict__ Wq, const float* __restrict__ Wk,
    const float* __restrict__ W1, unsigned short* __restrict__ Wfrag)
{
    __shared__ __align__(16) float Ws[128 * 132];
    __shared__ __align__(16) float W1s[8 * 128];
    const int tid = threadIdx.x;
    const int mat   = blockIdx.x & 1;
    const int hbase = (blockIdx.x >> 1) * 8;
    const float* Wsel = mat ? Wk : Wq;
#pragma unroll
    for (int q = 0; q < 16; ++q) {
        int f = tid + 256 * q;
        int i = f >> 5, c4 = (f & 31) * 4;
        *(float4*)(Ws + i * 132 + c4) = *(const float4*)(Wsel + (size_t)i * 128 + c4);
    }
#pragma unroll
    for (int q = 0; q < 4; ++q) {
        int f = tid + 256 * q;
        int hl = f >> 7, i = f & 127;
        W1s[hl * 128 + i] = W1[(size_t)(hbase + hl) * 260 + mat * 128 + i];
    }
    __syncthreads();
    const int hl = tid >> 5;
    const int h  = hbase + hl;
    const int j0 = (tid & 31) * 4;
    float4 acc = {0.f, 0.f, 0.f, 0.f};
    for (int i = 0; i < 128; ++i) {
        float c = W1s[hl * 128 + i];
        float4 w = *(const float4*)(Ws + i * 132 + j0);
        acc.x = fmaf(c, w.x, acc.x); acc.y = fmaf(c, w.y, acc.y);
        acc.z = fmaf(c, w.z, acc.z); acc.w = fmaf(c, w.w, acc.w);
    }
    const int nt = h >> 4;
    const unsigned base = 65536u + (unsigned)mat * 4096u;   // shorts
    float av[4] = {acc.x, acc.y, acc.z, acc.w};
#pragma unroll
    for (int jj = 0; jj < 4; ++jj) {
        int j = j0 + jj;
        int lane = (h & 15) | (((j >> 3) & 3) << 4);
        int ks = j >> 5, vj = j & 7;
        Wfrag[base + (unsigned)((nt * 4 + ks) * 64 + lane) * 8 + vj] = f2bf(av[jj]);
    }
}

__global__ __launch_bounds__(256, 4)
void gnn_fused(const float* __restrict__ x,
               const float* __restrict__ edge,
               const float* __restrict__ A_prior,
               const unsigned char* __restrict__ pad_mask,
               const unsigned short* __restrict__ Wfrag,
               const float* __restrict__ Wfuse,
               const float* __restrict__ W1,
               const float* __restrict__ b1,
               const float* __restrict__ W2,
               const float* __restrict__ b2,
               const float* __restrict__ gma,
               const float* __restrict__ bta,
               const float* __restrict__ physw,
               const float* __restrict__ priorw,
               float* __restrict__ out)
{
    __shared__ __align__(16) unsigned char arena[39648];
    // R_A [0,8192):      Zfrag bf16 A-frags (P0-P1 reads) -> Qs fp32 16x128 (P1w-P3) -> Sfrag bf16 (P6-P7)
    // R_B [8192,25088):  Ks fp32 32x132
    // R_C [25088,33280): Vfrag bf16 (P1w-P6) -> ThOut fp32 16x128 (P7-P8)
    // R_D [33280,38720): Lg fp32 16x33 | hqT bf16 [h][n] stride 18 | hks bf16 [m][h] stride 34
    unsigned short* Zfrag = (unsigned short*)(arena);
    float*          Qs    = (float*)(arena);
    unsigned short* Sfrag = (unsigned short*)(arena);
    float*          Ks    = (float*)(arena + 8192);
    unsigned short* Vfrag = (unsigned short*)(arena + 25088);
    float*          ThOut = (float*)(arena + 25088);
    float*          Lg    = (float*)(arena + 33280);
    unsigned short* hqT   = (unsigned short*)(arena + 35392);
    unsigned short* hks   = (unsigned short*)(arena + 36544);
    float4* W1e_s  = (float4*)(arena + 38720);
    float*  W2_s   = (float*)(arena + 39232);
    float*  b1s    = (float*)(arena + 39360);
    float*  maskrow= (float*)(arena + 39488);
    float*  Wf_s   = (float*)(arena + 39616);

    const int tid  = threadIdx.x;
    const int bt   = blockIdx.x >> 1;
    const int half = blockIdx.x & 1;
    const int b_ = bt >> 6, t_ = bt & 63;
    const float pw  = physw[0];
    const float rw_ = priorw[0];
    const float b2v = b2[0];

    // ---- P0: prefetch edge/prior (2 rows/thread); stage Z A-frags; small weights ----
    const int m3 = tid & 31, n23 = tid >> 5;
    float4 e4[2];
    float pr5[2][5];
#pragma unroll
    for (int r = 0; r < 2; ++r) {
        int ng = half * 16 + n23 * 2 + r;
        e4[r] = *(const float4*)(edge + (((size_t)bt * 32 + ng) * 32 + m3) * 4);
        size_t pb = (((size_t)bt * 32 + ng) * 32 + m3) * 5;
#pragma unroll
        for (int j5 = 0; j5 < 5; ++j5) pr5[r][j5] = A_prior[pb + j5];
    }
#pragma unroll
    for (int it = 0; it < 2; ++it) {
        int f = tid + 256 * it;             // chunk 0..511
        int lane9 = f & 63, ntk = f >> 6;
        int mm = lane9 & 15, qq = lane9 >> 4;
        int n = (ntk >> 2) * 16 + mm;
        int d = (ntk & 3) * 32 + qq * 8;
        const float* xr = x + ((size_t)((b_ * 32 + n) * 64 + t_)) * 128 + d;
        float4 a = *(const float4*)(xr);
        float4 b = *(const float4*)(xr + 4);
        uint4 pk;
        pk.x = pack2(a.x, a.y); pk.y = pack2(a.z, a.w);
        pk.z = pack2(b.x, b.y); pk.w = pack2(b.z, b.w);
        *(uint4*)(Zfrag + f * 8) = pk;
    }
    if (tid < 32) {
        int h = tid;
        W1e_s[h] = *(const float4*)(W1 + (size_t)h * 260 + 256);
        W2_s[h]  = W2[h];
        b1s[h]   = b1[h];
        maskrow[h] = pad_mask[b_ * 32 + h] ? 1.f : 0.f;
        if (h < 5) Wf_s[h] = Wfuse[h];
    }
    __syncthreads();

    const int wv = tid >> 6, lane = tid & 63;
    const int quad = lane >> 4, col0 = lane & 15;
    const bf16x8* Wf = (const bf16x8*)Wfrag;

    // ---- P1: K,V (32 tok), Q (16 rows), hq, hk — MFMA; Q/K stored fp32 ----
    {
        const int Mtk = wv & 1;
        const int ng4 = (wv >> 1) * 4;
        f32x4 zero = {0.f, 0.f, 0.f, 0.f};
        f32x4 aK[4] = {zero, zero, zero, zero};
        f32x4 aV[4] = {zero, zero, zero, zero};
        f32x4 aQ[2] = {zero, zero};
        f32x4 aHq = zero, aHk = zero;
#pragma unroll
        for (int ks = 0; ks < 4; ++ks) {
            bf16x8 avK = *(const bf16x8*)(Zfrag + ((Mtk * 4 + ks) * 64 + lane) * 8);
            bf16x8 avQ = *(const bf16x8*)(Zfrag + ((half * 4 + ks) * 64 + lane) * 8);
#pragma unroll
            for (int nt = 0; nt < 4; ++nt) {
                int bi = ((ng4 + nt) * 4 + ks) * 64 + lane;
                aK[nt] = __builtin_amdgcn_mfma_f32_16x16x32_bf16(avK, Wf[bi + 2048], aK[nt], 0, 0, 0);
                aV[nt] = __builtin_amdgcn_mfma_f32_16x16x32_bf16(avK, Wf[bi + 4096], aV[nt], 0, 0, 0);
            }
#pragma unroll
            for (int nt = 0; nt < 2; ++nt) {
                int bq = ((wv * 2 + nt) * 4 + ks) * 64 + lane;
                aQ[nt] = __builtin_amdgcn_mfma_f32_16x16x32_bf16(avQ, Wf[bq], aQ[nt], 0, 0, 0);
            }
            if (wv < 2)
                aHq = __builtin_amdgcn_mfma_f32_16x16x32_bf16(avQ, Wf[8192 + (wv * 4 + ks) * 64 + lane], aHq, 0, 0, 0);
            aHk = __builtin_amdgcn_mfma_f32_16x16x32_bf16(avK, Wf[8704 + ((wv >> 1) * 4 + ks) * 64 + lane], aHk, 0, 0, 0);
        }
        __syncthreads();   // all Zfrag reads complete; R_A may be overwritten (Qs)
#pragma unroll
        for (int nt = 0; nt < 4; ++nt) {
            int colc = (ng4 + nt) * 16 + col0;
            int vks = colc >> 5, vq = (colc >> 3) & 3, vj = colc & 7;
#pragma unroll
            for (int reg = 0; reg < 4; ++reg) {
                int row = Mtk * 16 + quad * 4 + reg;          // key token 0..31
                Ks[row * 132 + colc] = aK[nt][reg];
                int idx = (Mtk * 4 + vks) * 64 + vq * 16 + (quad * 4 + reg);
                Vfrag[idx * 8 + vj] = f2bf(aV[nt][reg]);
            }
        }
#pragma unroll
        for (int nt = 0; nt < 2; ++nt) {
            int colc = (wv * 2 + nt) * 16 + col0;
#pragma unroll
            for (int reg = 0; reg < 4; ++reg)
                Qs[(quad * 4 + reg) * 128 + colc] = aQ[nt][reg];  // local Q row 0..15
        }
        if (wv < 2) {
            int h = wv * 16 + col0;
#pragma unroll
            for (int reg = 0; reg < 4; ++reg)
                hqT[h * 18 + (quad * 4 + reg)] = f2bf(aHq[reg] + b1s[h]);
        }
        {
            int h = (wv >> 1) * 16 + col0;
#pragma unroll
            for (int reg = 0; reg < 4; ++reg)
                hks[(Mtk * 16 + quad * 4 + reg) * 34 + h] = f2bf(aHk[reg]);
        }
    }
    __syncthreads();

    // ---- P3: logits = QK^T/sqrt(d) (fp32 VALU) + pw*phys + rw*log(prior), masked ----
    {
        const int m = m3, n2 = n23;
        const float* krow = Ks + m * 132;
        const float* q0 = Qs + (n2 * 2) * 128;
        const float* q1 = Qs + (n2 * 2 + 1) * 128;
        float acc0 = 0.f, acc1 = 0.f;
        for (int j = 0; j < 128; j += 4) {
            float4 k4 = *(const float4*)(krow + j);
            float4 qa = *(const float4*)(q0 + j);
            float4 qb = *(const float4*)(q1 + j);
            acc0 = fmaf(qa.x, k4.x, fmaf(qa.y, k4.y, fmaf(qa.z, k4.z, fmaf(qa.w, k4.w, acc0))));
            acc1 = fmaf(qb.x, k4.x, fmaf(qb.y, k4.y, fmaf(qb.z, k4.z, fmaf(qb.w, k4.w, acc1))));
        }
        float pacc[2] = {0.f, 0.f};
        for (int h = 0; h < 32; ++h) {
            float4 we = W1e_s[h];
            float w2v = W2_s[h];
            float hkv = bf2f(hks[m * 34 + h]);
            float hq0 = bf2f(hqT[h * 18 + n2 * 2]);
            float hq1 = bf2f(hqT[h * 18 + n2 * 2 + 1]);
            float he0 = fmaf(e4[0].x, we.x, fmaf(e4[0].y, we.y, fmaf(e4[0].z, we.z, e4[0].w * we.w)));
            float he1 = fmaf(e4[1].x, we.x, fmaf(e4[1].y, we.y, fmaf(e4[1].z, we.z, e4[1].w * we.w)));
            pacc[0] = fmaf(fmaxf(hq0 + hkv + he0, 0.f), w2v, pacc[0]);
            pacc[1] = fmaf(fmaxf(hq1 + hkv + he1, 0.f), w2v, pacc[1]);
        }
        float cont[2] = {acc0, acc1};
#pragma unroll
        for (int r = 0; r < 2; ++r) {
            int nloc = n2 * 2 + r, ng = half * 16 + nloc;
            float pr = pr5[r][0]*Wf_s[0] + pr5[r][1]*Wf_s[1] + pr5[r][2]*Wf_s[2]
                     + pr5[r][3]*Wf_s[3] + pr5[r][4]*Wf_s[4];
            if (!(fabsf(pr) < 1e30f)) pr = 0.f;
            pr = fmaxf(pr, 0.f);
            float lg = cont[r] * 0.08838834764831845f
                     + pw * (pacc[r] + b2v) + rw_ * __logf(pr + 1e-6f);
            if (maskrow[ng] != 0.f || maskrow[m] != 0.f) lg = -1e9f;
            Lg[nloc * 33 + m] = lg;
        }
    }
    __syncthreads();

    // ---- P4: softmax (16 rows) ----
    if (tid < 16) {
        const int n = tid;
        float mx = -3.4e38f;
        for (int m2 = 0; m2 < 32; ++m2) mx = fmaxf(mx, Lg[n * 33 + m2]);
        float s = 0.f;
        for (int m2 = 0; m2 < 32; ++m2) {
            float e = __expf(Lg[n * 33 + m2] - mx);
            Lg[n * 33 + m2] = e; s += e;
        }
        float inv = 1.f / s;
        for (int m2 = 0; m2 < 32; ++m2) Lg[n * 33 + m2] *= inv;
    }
    __syncthreads();

    // ---- P6: spatial = alpha @ V (2 rows/thread) -> bf16 A-frags into Sfrag (R_A; Qs dead) ----
    {
        const int d0 = (tid & 31) * 4, nl0 = (tid >> 5) * 2;
        const int vks = d0 >> 5, vq = (d0 >> 3) & 3, vj = d0 & 7;
        float sa[2][4] = {{0,0,0,0},{0,0,0,0}};
        for (int m = 0; m < 32; ++m) {
            int idx = ((m >> 4) * 4 + vks) * 64 + vq * 16 + (m & 15);
            const unsigned short* vp = Vfrag + idx * 8 + vj;
            float v0 = bf2f(vp[0]), v1 = bf2f(vp[1]), v2 = bf2f(vp[2]), v3 = bf2f(vp[3]);
            float a0 = Lg[nl0 * 33 + m], a1 = Lg[(nl0 + 1) * 33 + m];
            sa[0][0]=fmaf(a0,v0,sa[0][0]); sa[0][1]=fmaf(a0,v1,sa[0][1]);
            sa[0][2]=fmaf(a0,v2,sa[0][2]); sa[0][3]=fmaf(a0,v3,sa[0][3]);
            sa[1][0]=fmaf(a1,v0,sa[1][0]); sa[1][1]=fmaf(a1,v1,sa[1][1]);
            sa[1][2]=fmaf(a1,v2,sa[1][2]); sa[1][3]=fmaf(a1,v3,sa[1][3]);
        }
#pragma unroll
        for (int r = 0; r < 2; ++r) {
            int nloc = nl0 + r;
            unsigned short* sp = Sfrag + (vks * 64 + vq * 16 + nloc) * 8 + vj;
            sp[0] = f2bf(sa[r][0]); sp[1] = f2bf(sa[r][1]);
            sp[2] = f2bf(sa[r][2]); sp[3] = f2bf(sa[r][3]);
        }
    }
    __syncthreads();

    // ---- P7: Theta MFMA (16 rows) -> ThOut fp32 (R_C; Vfrag dead) ----
    {
        f32x4 aT[2] = {{0.f,0.f,0.f,0.f},{0.f,0.f,0.f,0.f}};
#pragma unroll
        for (int ks = 0; ks < 4; ++ks) {
            bf16x8 av = *(const bf16x8*)(Sfrag + (ks * 64 + lane) * 8);
#pragma unroll
            for (int nt = 0; nt < 2; ++nt)
                aT[nt] = __builtin_amdgcn_mfma_f32_16x16x32_bf16(
                    av, Wf[6144 + ((wv * 2 + nt) * 4 + ks) * 64 + lane], aT[nt], 0, 0, 0);
        }
#pragma unroll
        for (int nt = 0; nt < 2; ++nt) {
            int colc = (wv * 2 + nt) * 16 + col0;
#pragma unroll
            for (int reg = 0; reg < 4; ++reg)
                ThOut[(quad * 4 + reg) * 128 + colc] = aT[nt][reg];
        }
    }
    __syncthreads();

    // ---- P8: y = x + ThOut; LayerNorm; mask; store (2 rows/thread) ----
    {
        const int d0 = (tid & 31) * 4, n2 = tid >> 5;
        float4 g4  = *(const float4*)(gma + d0);
        float4 be4 = *(const float4*)(bta + d0);
#pragma unroll
        for (int r = 0; r < 2; ++r) {
            int nloc = n2 * 2 + r, ng = half * 16 + nloc;
            const float* xr = x + ((size_t)((b_ * 32 + ng) * 64 + t_)) * 128 + d0;
            float4 z  = *(const float4*)(xr);
            float4 th = *(const float4*)(ThOut + nloc * 128 + d0);
            float y0 = th.x + z.x, y1 = th.y + z.y, y2 = th.z + z.z, y3 = th.w + z.w;
            float s  = (y0 + y1) + (y2 + y3);
            float s2 = (y0*y0 + y1*y1) + (y2*y2 + y3*y3);
#pragma unroll
            for (int off = 1; off < 32; off <<= 1) {
                s  += __shfl_xor(s,  off, 64);
                s2 += __shfl_xor(s2, off, 64);
            }
            float mu   = s * 0.0078125f;
            float var  = s2 * 0.0078125f - mu * mu;
            float rstd = rsqrtf(var + 1e-5f);
            float msk  = (maskrow[ng] != 0.f) ? 0.f : 1.f;
            float4 o;
            o.x = ((y0 - mu) * rstd * g4.x + be4.x) * msk;
            o.y = ((y1 - mu) * rstd * g4.y + be4.y) * msk;
            o.z = ((y2 - mu) * rstd * g4.z + be4.z) * msk;
            o.w = ((y3 - mu) * rstd * g4.w + be4.w) * msk;
            *(float4*)(out + ((size_t)((b_ * 32 + ng) * 64 + t_)) * 128 + d0) = o;
        }
    }
}

extern "C" void kernel_launch(void* const* d_in, const int* in_sizes, int n_in,
                              void* d_out, int out_size, void* d_ws, size_t ws_size,
                              hipStream_t stream) {
    const float* x        = (const float*)d_in[0];
    const float* edge     = (const float*)d_in[1];
    const float* A_prior  = (const float*)d_in[2];
    const unsigned char* pad_mask = (const unsigned char*)d_in[3];
    const float* Wq       = (const float*)d_in[4];
    const float* Wk       = (const float*)d_in[5];
    const float* Wv       = (const float*)d_in[6];
    const float* Theta    = (const float*)d_in[7];
    const float* Wfuse    = (const float*)d_in[8];
    const float* W1       = (const float*)d_in[9];
    const float* b1       = (const float*)d_in[10];
    const float* W2       = (const float*)d_in[11];
    const float* b2       = (const float*)d_in[12];
    const float* gma      = (const float*)d_in[13];
    const float* bta      = (const float*)d_in[14];
    const float* physw    = (const float*)d_in[15];
    const float* priorw   = (const float*)d_in[16];
    float* out = (float*)d_out;

    unsigned short* Wfrag = (unsigned short*)d_ws;   // 73728 shorts = 144 KB

    k0a_pack_w<<<dim3(32), dim3(256), 0, stream>>>(Wq, Wk, Wv, Theta, Wfrag);
    k0b_compose<<<dim3(8), dim3(256), 0, stream>>>(Wq, Wk, W1, Wfrag);
    gnn_fused<<<dim3(1024), dim3(256), 0, stream>>>(
        x, edge, A_prior, pad_mask, Wfrag, Wfuse,
        W1, b1, W2, b2, gma, bta, physw, priorw, out);
}